// Round 7
// baseline (223.662 us; speedup 1.0000x reference)
//
#include <hip/hip_runtime.h>

#define NN 100
#define CC 256
#define NKK 103
#define LSA 72     // K1 staging stride (bf16)
#define LDPW 136   // K2 PW stride (bf16): 272B rows, 16B-aligned frags
#define OTS 260    // out-transpose stride (f32)
#define PWLD 112   // ws pw row width (bf16)

typedef __bf16 bf16;
typedef __bf16 bf16x4 __attribute__((ext_vector_type(4)));
typedef __bf16 bf16x8 __attribute__((ext_vector_type(8)));
typedef float f32x4 __attribute__((ext_vector_type(4)));

// ---------------- K1: dy = q @ W + bias -> pw(bf16)/dw(f32) in ws ----------------
__global__ __launch_bounds__(512, 4)
void k1_gemm1(const float* __restrict__ query, const float* __restrict__ W,
              const float* __restrict__ bwl,
              bf16* __restrict__ ws_pw, float* __restrict__ ws_dw)
{
    __shared__ __align__(16) bf16 R[100 * LSA + NKK * LSA];   // 29232 B
    bf16* Abuf = R;
    bf16* Wbuf = R + 100 * LSA;

    const int t    = threadIdx.x;
    const int w    = t >> 6;
    const int lane = t & 63;
    const int ln16 = lane & 15;
    const int g    = lane >> 4;
    const int hi8  = g * 8;
    const int b    = blockIdx.x;
    const float* qb = query + (size_t)b * NN * CC;

    f32x4 acc1[7];
    #pragma unroll
    for (int I = 0; I < 7; ++I) acc1[I] = (f32x4){0.f, 0.f, 0.f, 0.f};

    for (int kc = 0; kc < 4; ++kc) {
        const int k0 = kc * 64;
        __syncthreads();
        {   // query chunk: 1600 f32x4 items, coalesced
            f32x4 qv[4];
            #pragma unroll
            for (int p = 0; p < 4; ++p) {
                int idx = p * 512 + t;
                if (idx < 1600) {
                    int r = idx >> 4, j = (idx & 15) << 2;
                    qv[p] = *(const f32x4*)(qb + r * CC + k0 + j);
                }
            }
            #pragma unroll
            for (int p = 0; p < 4; ++p) {
                int idx = p * 512 + t;
                if (idx < 1600) {
                    int r = idx >> 4, j = (idx & 15) << 2;
                    bf16x4 s;
                    #pragma unroll
                    for (int i = 0; i < 4; ++i) s[i] = (bf16)qv[p][i];
                    *(bf16x4*)&Abuf[r * LSA + j] = s;
                }
            }
        }
        {   // W chunk: 64x103, coalesced load, transposed scatter
            float wv[13];
            #pragma unroll
            for (int p = 0; p < 13; ++p) {
                int idx = p * 512 + t;
                if (idx < 64 * NKK) {
                    int kk = idx / NKK, ka = idx - kk * NKK;
                    wv[p] = W[(size_t)(k0 + kk) * NKK + ka];
                }
            }
            #pragma unroll
            for (int p = 0; p < 13; ++p) {
                int idx = p * 512 + t;
                if (idx < 64 * NKK) {
                    int kk = idx / NKK, ka = idx - kk * NKK;
                    Wbuf[ka * LSA + kk] = (bf16)wv[p];
                }
            }
        }
        __syncthreads();

        if (w < 7) {
            const int rB = (w * 16 + ln16 < NKK) ? (w * 16 + ln16) : (NKK - 1);
            #pragma unroll
            for (int s = 0; s < 2; ++s) {
                bf16x8 bv = *(const bf16x8*)&Wbuf[rB * LSA + s * 32 + hi8];
                #pragma unroll
                for (int I = 0; I < 7; ++I) {
                    int row = I * 16 + ln16;
                    row = (row < NN) ? row : (NN - 1);
                    bf16x8 av = *(const bf16x8*)&Abuf[row * LSA + s * 32 + hi8];
                    acc1[I] = __builtin_amdgcn_mfma_f32_16x16x32_bf16(av, bv, acc1[I], 0, 0, 0);
                }
            }
        }
    }
    __syncthreads();   // all staging reads done -> R reused below

    // epilogue: acc -> LDS tile (aliases R), then coalesced global writes
    bf16*  PWs = R;                                  // [100][112] bf16 = 22400 B
    float* DWs = (float*)((char*)R + NN * PWLD * 2); // 300 f32 at byte 22400
    if (w < 7) {
        const int kap = w * 16 + ln16;
        const float bw = (kap < NKK) ? bwl[kap] : 0.f;
        #pragma unroll
        for (int I = 0; I < 7; ++I) {
            #pragma unroll
            for (int r = 0; r < 4; ++r) {
                int n = I * 16 + g * 4 + r;
                if (n < NN && kap < NKK) {
                    float v = acc1[I][r] + bw;
                    if (kap < 3) DWs[n * 3 + kap] = v;
                    else         PWs[n * PWLD + (kap - 3)] = (bf16)v;
                }
            }
        }
    }
    __syncthreads();
    bf16* gpw = ws_pw + (size_t)b * NN * PWLD;
    for (int u = t; u < 1400; u += 512)                 // 100*112/8 = 1400 16B units
        *(bf16x8*)(gpw + u * 8) = *(const bf16x8*)&PWs[u * 8];   // pad cols garbage; K2 re-zeros
    if (t < 300) ws_dw[b * 300 + t] = DWs[t];
}

// ---------------- K2: depth = relu(conv(dw, value)); out = LN(pw @ depth) ----------------
__global__ __launch_bounds__(512, 4)
void k2_conv_gemm2_ln(const float* __restrict__ value,
                      const bf16* __restrict__ ws_pw, const float* __restrict__ ws_dw,
                      const float* __restrict__ gamma, const float* __restrict__ beta,
                      float* __restrict__ out)
{
    // LDS: 27200 + 1200 + 6400 + 800 + 16640 = 52240 B
    __shared__ __align__(16) bf16 PW[NN * LDPW];
    __shared__ float DW[NN][3];
    __shared__ float RP[8][NN][2];
    __shared__ float RS[NN][2];
    __shared__ __align__(16) float OT[16 * OTS];

    const int t    = threadIdx.x;
    const int w    = t >> 6;
    const int lane = t & 63;
    const int ln16 = lane & 15;
    const int g    = lane >> 4;
    const int hi8  = g * 8;
    const int b    = blockIdx.x;
    const float* vb = value + (size_t)b * NN * CC;

    // stage pw (valid 13 units/row; unit 13 = pure pad, skipped) + dw
    const bf16* gpw = ws_pw + (size_t)b * NN * PWLD;
    for (int u = t; u < 1300; u += 512) {
        int row = u / 13, cu = u - (u / 13) * 13;
        *(bf16x8*)&PW[row * LDPW + cu * 8] = *(const bf16x8*)(gpw + row * PWLD + cu * 8);
    }
    if (t < 300) DW[t / 3][t % 3] = ws_dw[b * 300 + t];
    __syncthreads();
    // zero k-pad cols 100..127 (staging wrote garbage into 100..103; GEMM2 reads to col 127)
    for (int i = t; i < NN * 28; i += 512) {
        int r = i / 28, c = 100 + (i - (i / 28) * 28);
        PW[r * LDPW + c] = (bf16)0.f;
    }
    __syncthreads();

    // conv (register B-layout) + GEMM2
    f32x4 acc2[2][7];
    #pragma unroll
    for (int st = 0; st < 2; ++st)
        #pragma unroll
        for (int I = 0; I < 7; ++I) acc2[st][I] = (f32x4){0.f, 0.f, 0.f, 0.f};

    const int cb = w * 16 + ln16;    // st0: cb (0..127), st1: cb+128
    for (int ks = 0; ks < 4; ++ks) {
        float xv[8], yv[8];
        #pragma unroll
        for (int j = 0; j < 8; ++j) {
            int m = ks * 32 + hi8 + j;
            bool mv = (m < NN);
            const float* vr = vb + m * CC;
            xv[j] = mv ? vr[cb]       : 0.f;
            yv[j] = mv ? vr[cb + 128] : 0.f;
        }
        bf16x8 dv0, dv1;
        #pragma unroll
        for (int j = 0; j < 8; ++j) {
            int  m  = ks * 32 + hi8 + j;
            bool mv = (m < NN);
            int  mc = mv ? m : (NN - 1);
            float w0 = DW[mc][0], w1 = DW[mc][1], w2 = DW[mc][2];
            float x0 = xv[j], y0 = yv[j];
            float xm = __shfl(x0, (lane - 1) & 63), xp = __shfl(x0, (lane + 1) & 63);
            float ym = __shfl(y0, (lane - 1) & 63), yp = __shfl(y0, (lane + 1) & 63);
            if (ln16 == 0) {
                xm = (mv && cb > 0) ? vb[m * CC + cb - 1] : 0.f;
                ym = mv ? vb[m * CC + cb + 127] : 0.f;
            }
            if (ln16 == 15) {
                xp = mv ? vb[m * CC + cb + 1] : 0.f;
                yp = (mv && cb + 129 < CC) ? vb[m * CC + cb + 129] : 0.f;
            }
            float d0 = w0 * xm + w1 * x0 + w2 * xp;
            float d1 = w0 * ym + w1 * y0 + w2 * yp;
            dv0[j] = (bf16)(mv ? fmaxf(d0, 0.f) : 0.f);
            dv1[j] = (bf16)(mv ? fmaxf(d1, 0.f) : 0.f);
        }
        #pragma unroll
        for (int I = 0; I < 7; ++I) {
            int row = I * 16 + ln16;
            row = (row < NN) ? row : (NN - 1);
            bf16x8 af = *(const bf16x8*)&PW[row * LDPW + ks * 32 + hi8];
            acc2[0][I] = __builtin_amdgcn_mfma_f32_16x16x32_bf16(af, dv0, acc2[0][I], 0, 0, 0);
            acc2[1][I] = __builtin_amdgcn_mfma_f32_16x16x32_bf16(af, dv1, acc2[1][I], 0, 0, 0);
        }
    }

    // LayerNorm
    #pragma unroll
    for (int I = 0; I < 7; ++I) {
        #pragma unroll
        for (int r = 0; r < 4; ++r) {
            float a = acc2[0][I][r], e = acc2[1][I][r];
            float s1 = a + e, s2 = a * a + e * e;
            #pragma unroll
            for (int mk = 1; mk < 16; mk <<= 1) {
                s1 += __shfl_xor(s1, mk);
                s2 += __shfl_xor(s2, mk);
            }
            int n = I * 16 + g * 4 + r;
            if (ln16 == 0 && n < NN) {
                RP[w][n][0] = s1;
                RP[w][n][1] = s2;
            }
        }
    }
    __syncthreads();
    if (t < NN) {
        float S1 = 0.f, S2 = 0.f;
        #pragma unroll
        for (int wi = 0; wi < 8; ++wi) { S1 += RP[wi][t][0]; S2 += RP[wi][t][1]; }
        float mu  = S1 * (1.f / 256.f);
        float var = S2 * (1.f / 256.f) - mu * mu;
        RS[t][0] = mu;
        RS[t][1] = rsqrtf(fmaxf(var, 0.f) + 1e-5f);
    }
    __syncthreads();

    // normalize + transpose through LDS -> coalesced f32x4 stores
    const float gm0 = gamma[cb], gm1 = gamma[cb + 128];
    const float bt0 = beta[cb],  bt1 = beta[cb + 128];
    float* ob = out + (size_t)b * NN * CC;
    #pragma unroll
    for (int I = 0; I < 7; ++I) {
        #pragma unroll
        for (int r = 0; r < 4; ++r) {
            int n = I * 16 + g * 4 + r;
            if (n < NN) {
                float mu = RS[n][0], rs = RS[n][1];
                int rt = g * 4 + r;
                OT[rt * OTS + cb]       = (acc2[0][I][r] - mu) * rs * gm0 + bt0;
                OT[rt * OTS + cb + 128] = (acc2[1][I][r] - mu) * rs * gm1 + bt1;
            }
        }
        __syncthreads();
        #pragma unroll
        for (int p = 0; p < 2; ++p) {
            int idx  = p * 512 + t;
            int row  = idx >> 6, c4 = (idx & 63) << 2;
            int grow = I * 16 + row;
            if (grow < NN)
                *(f32x4*)(ob + grow * CC + c4) = *(const f32x4*)&OT[row * OTS + c4];
        }
        __syncthreads();
    }
}

extern "C" void kernel_launch(void* const* d_in, const int* in_sizes, int n_in,
                              void* d_out, int out_size, void* d_ws, size_t ws_size,
                              hipStream_t stream) {
    const float* query = (const float*)d_in[0];
    const float* value = (const float*)d_in[1];
    const float* W     = (const float*)d_in[2];
    const float* bwl   = (const float*)d_in[3];
    const float* gamma = (const float*)d_in[4];
    const float* beta  = (const float*)d_in[5];

    bf16*  ws_pw = (bf16*)d_ws;                                        // 512*100*112 bf16 = 11.47 MB
    float* ws_dw = (float*)((char*)d_ws + (size_t)512 * NN * PWLD * 2); // +0.61 MB

    k1_gemm1<<<dim3(512), dim3(512), 0, stream>>>(query, W, bwl, ws_pw, ws_dw);
    k2_conv_gemm2_ln<<<dim3(512), dim3(512), 0, stream>>>(value, ws_pw, ws_dw, gamma, beta, (float*)d_out);
}